// Round 6
// baseline (16.572 us; speedup 1.0000x reference)
//
#include <hip/hip_runtime.h>
#include <math.h>

#define LL 500
#define BB 4
#define EE 100000
#define NBINS 24
#define BLOCK 256
#define CHUNK 512                    // edges per block (2 per thread)
#define NCHUNK ((EE + CHUNK - 1) / CHUNK)   // 196
#define GRID1 (BB * NCHUNK)          // 784
#define CF (LL * 3)                  // 1500 floats per batch per array

struct f3 { float x, y, z; };

__device__ __forceinline__ f3 sub3(f3 a, f3 b) {
    f3 r; r.x = a.x - b.x; r.y = a.y - b.y; r.z = a.z - b.z; return r;
}
__device__ __forceinline__ f3 cross3(f3 a, f3 b) {
    f3 r;
    r.x = a.y * b.z - a.z * b.y;
    r.y = a.z * b.x - a.x * b.z;
    r.z = a.x * b.y - a.y * b.x;
    return r;
}
__device__ __forceinline__ float dot3(f3 a, f3 b) {
    return fmaf(a.x, b.x, fmaf(a.y, b.y, a.z * b.z));
}

__device__ __forceinline__ float item_val(
    const float* __restrict__ lN, const float* __restrict__ lCA,
    const float* __restrict__ lCB, const float* __restrict__ coeff,
    int x, int y)
{
    f3 xN, xCA, xCB, yCB;
    xN.x  = lN [3 * x];     xN.y  = lN [3 * x + 1]; xN.z  = lN [3 * x + 2];
    xCA.x = lCA[3 * x];     xCA.y = lCA[3 * x + 1]; xCA.z = lCA[3 * x + 2];
    xCB.x = lCB[3 * x];     xCB.y = lCB[3 * x + 1]; xCB.z = lCB[3 * x + 2];
    yCB.x = lCB[3 * y];     yCB.y = lCB[3 * y + 1]; yCB.z = lCB[3 * y + 2];

    const f3 b1 = sub3(xCA, xN);
    const f3 b2 = sub3(xCB, xCA);
    const f3 b3 = sub3(yCB, xCB);

    const f3 n1 = cross3(b1, b2);
    const f3 n2 = cross3(b2, b3);

    const float rn = rsqrtf(dot3(b2, b2));
    const f3 m = cross3(n1, b2);
    const float s = dot3(m, n2) * rn;
    const float c = dot3(n1, n2);

    const float theta = atan2f(s, c);

    const float step  = 0.261799387799149436f;      // 15 * pi / 180
    const float c0    = -3.14159265358979324f + 0.5f * step;
    const float twoPi = 6.28318530717958648f;

    const float tw = (theta < c0) ? theta + twoPi : theta;

    int seg = (int)floorf((tw - c0) / step);
    seg = seg < 0 ? 0 : (seg > NBINS - 1 ? NBINS - 1 : seg);

    const float t = tw - (c0 + (float)seg * step);

    const float4 cs = *reinterpret_cast<const float4*>(
        coeff + (((size_t)x * LL + (size_t)y) * NBINS + (size_t)seg) * 4);

    return fmaf(fmaf(fmaf(cs.w, t, cs.z), t, cs.y), t, cs.x);
}

__global__ void __launch_bounds__(BLOCK) theta_partial_kernel(
    const float* __restrict__ N,
    const float* __restrict__ CA,
    const float* __restrict__ CB,
    const float* __restrict__ coeff,
    const int* __restrict__ x_idx,
    const int* __restrict__ y_idx,
    float* __restrict__ partials)
{
    const int b     = blockIdx.x & 3;        // batch for this block
    const int chunk = blockIdx.x >> 2;       // edge chunk

    // Stage THIS batch's coords: 3 x 1500 floats = 18 KB -> high occupancy.
    __shared__ float lds[3 * CF];
    {
        const float4* s0 = reinterpret_cast<const float4*>(N  + b * CF);
        const float4* s1 = reinterpret_cast<const float4*>(CA + b * CF);
        const float4* s2 = reinterpret_cast<const float4*>(CB + b * CF);
        float4* d0 = reinterpret_cast<float4*>(&lds[0]);
        float4* d1 = reinterpret_cast<float4*>(&lds[CF]);
        float4* d2 = reinterpret_cast<float4*>(&lds[2 * CF]);
        for (int j = threadIdx.x; j < CF / 4; j += BLOCK) {   // 375 float4 each
            d0[j] = s0[j];
            d1[j] = s1[j];
            d2[j] = s2[j];
        }
    }
    __syncthreads();

    const float* lN  = &lds[0];
    const float* lCA = &lds[CF];
    const float* lCB = &lds[2 * CF];

    const int e0 = chunk * CHUNK + threadIdx.x;
    const int e1 = e0 + BLOCK;

    float acc = 0.0f;
    // two independent chains (ILP): idx loads + gathers overlap
    if (e0 < EE) {
        const int x0 = x_idx[e0], y0 = y_idx[e0];
        acc += item_val(lN, lCA, lCB, coeff, x0, y0);
    }
    if (e1 < EE) {
        const int x1 = x_idx[e1], y1 = y_idx[e1];
        acc += item_val(lN, lCA, lCB, coeff, x1, y1);
    }

    // wave64 reduction
    #pragma unroll
    for (int off = 32; off > 0; off >>= 1)
        acc += __shfl_down(acc, off, 64);

    __shared__ float wsum[BLOCK / 64];
    const int lane = threadIdx.x & 63;
    const int wid  = threadIdx.x >> 6;
    if (lane == 0) wsum[wid] = acc;
    __syncthreads();
    if (threadIdx.x == 0)
        partials[blockIdx.x] = wsum[0] + wsum[1] + wsum[2] + wsum[3];
}

__global__ void __launch_bounds__(BLOCK) theta_reduce_kernel(
    const float* __restrict__ partials,
    float* __restrict__ out)
{
    float v = 0.0f;
    for (int i = threadIdx.x; i < GRID1; i += BLOCK)
        v += partials[i];

    #pragma unroll
    for (int off = 32; off > 0; off >>= 1)
        v += __shfl_down(v, off, 64);

    __shared__ float wsum[BLOCK / 64];
    const int lane = threadIdx.x & 63;
    const int wid  = threadIdx.x >> 6;
    if (lane == 0) wsum[wid] = v;
    __syncthreads();
    if (threadIdx.x == 0)
        out[0] = wsum[0] + wsum[1] + wsum[2] + wsum[3];
}

extern "C" void kernel_launch(void* const* d_in, const int* in_sizes, int n_in,
                              void* d_out, int out_size, void* d_ws, size_t ws_size,
                              hipStream_t stream) {
    const float* N     = (const float*)d_in[0];
    const float* CA    = (const float*)d_in[1];
    const float* CB    = (const float*)d_in[2];
    const float* coeff = (const float*)d_in[3];
    const int* x_idx   = (const int*)d_in[4];
    const int* y_idx   = (const int*)d_in[5];
    float* out      = (float*)d_out;
    float* partials = (float*)d_ws;   // GRID1 floats, write-before-read each call

    theta_partial_kernel<<<GRID1, BLOCK, 0, stream>>>(N, CA, CB, coeff,
                                                      x_idx, y_idx, partials);
    theta_reduce_kernel<<<1, BLOCK, 0, stream>>>(partials, out);
}